// Round 1
// baseline (126.328 us; speedup 1.0000x reference)
//
#include <hip/hip_runtime.h>
#include <cfloat>

#define TPB 256
#define CHUNK 2048
#define ALPHA 0.5f

// Kernel 1: for each query element q (first n queries are x vs y, next m are
// y vs x), compute min over a CHUNK-sized slice of the database and atomically
// fold into mins[q]. Database index is wave-uniform -> scalar loads (s_load),
// inner loop is pure VALU: v_sub + v_min3(abs,abs) = 1.5 instr/element.
__global__ void chamfer_min_kernel(const float* __restrict__ x,
                                   const float* __restrict__ y,
                                   int n, int m,
                                   unsigned int* __restrict__ mins) {
    const int q = blockIdx.y * TPB + threadIdx.x;
    const int total = n + m;
    if (q >= total) return;

    const float* __restrict__ db;
    int dbn;
    float qv;
    if (q < n) { qv = x[q];      db = y; dbn = m; }
    else       { qv = y[q - n];  db = x; dbn = n; }

    const int start = blockIdx.x * CHUNK;
    if (start >= dbn) return;
    const int end = min(start + CHUNK, dbn);

    // 4 independent accumulators to break the v_min3 dependency chain.
    float m0 = FLT_MAX, m1 = FLT_MAX, m2 = FLT_MAX, m3 = FLT_MAX;
    int j = start;
    for (; j + 8 <= end; j += 8) {
        // Uniform loads -> s_load_dwordx8, operands broadcast from SGPRs.
        const float v0 = db[j + 0], v1 = db[j + 1];
        const float v2 = db[j + 2], v3 = db[j + 3];
        const float v4 = db[j + 4], v5 = db[j + 5];
        const float v6 = db[j + 6], v7 = db[j + 7];
        m0 = fminf(fminf(m0, fabsf(qv - v0)), fabsf(qv - v1));
        m1 = fminf(fminf(m1, fabsf(qv - v2)), fabsf(qv - v3));
        m2 = fminf(fminf(m2, fabsf(qv - v4)), fabsf(qv - v5));
        m3 = fminf(fminf(m3, fabsf(qv - v6)), fabsf(qv - v7));
    }
    for (; j < end; ++j) m0 = fminf(m0, fabsf(qv - db[j]));
    const float mbest = fminf(fminf(m0, m1), fminf(m2, m3));

    // Non-negative float bit patterns order identically as unsigned ints.
    atomicMin(&mins[q], __float_as_uint(mbest));
}

// Kernel 2: reduce the 32768 per-query mins into the scalar loss.
__global__ void chamfer_reduce_kernel(const unsigned int* __restrict__ mins,
                                      int n, int m, float* __restrict__ out) {
    const int total = n + m;
    double sx = 0.0, sy = 0.0;
    for (int i = threadIdx.x; i < total; i += blockDim.x) {
        const float v = __uint_as_float(mins[i]);
        if (i < n) sx += (double)v; else sy += (double)v;
    }
    // Wave-64 shuffle reduction.
    for (int off = 32; off > 0; off >>= 1) {
        sx += __shfl_down(sx, off);
        sy += __shfl_down(sy, off);
    }
    __shared__ double lsx[16], lsy[16];
    const int wave = threadIdx.x >> 6;
    if ((threadIdx.x & 63) == 0) { lsx[wave] = sx; lsy[wave] = sy; }
    __syncthreads();
    if (threadIdx.x == 0) {
        double tx = 0.0, ty = 0.0;
        const int nw = blockDim.x >> 6;
        for (int w = 0; w < nw; ++w) { tx += lsx[w]; ty += lsy[w]; }
        const double a = (double)ALPHA;
        out[0] = (float)(a * tx / (double)n + (1.0 - a) * ty / (double)m);
    }
}

extern "C" void kernel_launch(void* const* d_in, const int* in_sizes, int n_in,
                              void* d_out, int out_size, void* d_ws, size_t ws_size,
                              hipStream_t stream) {
    const float* x = (const float*)d_in[0];
    const float* y = (const float*)d_in[1];
    const int n = in_sizes[0];
    const int m = in_sizes[1];
    unsigned int* mins = (unsigned int*)d_ws;
    float* out = (float*)d_out;

    const int total = n + m;
    // 0xFFFFFFFF == uint max == +inf for our unsigned atomicMin.
    hipMemsetAsync(mins, 0xFF, (size_t)total * sizeof(unsigned int), stream);

    const int maxdb = n > m ? n : m;
    dim3 grid1((maxdb + CHUNK - 1) / CHUNK, (total + TPB - 1) / TPB);
    chamfer_min_kernel<<<grid1, TPB, 0, stream>>>(x, y, n, m, mins);

    chamfer_reduce_kernel<<<1, 1024, 0, stream>>>(mins, n, m, out);
}

// Round 2
// 120.258 us; speedup vs baseline: 1.0505x; 1.0505x over previous
//
#include <hip/hip_runtime.h>
#include <cfloat>

#define TPB 256
#define Q 8          // queries per thread (register tile)
#define CHUNKS 64    // db chunks (parallelism dimension)
#define NB2 32       // reduce1 blocks
#define ALPHA 0.5f

// ---------------------------------------------------------------------------
// Scan core: 8 queries per thread, db slice read via wave-uniform (scalar)
// loads. Per 8 db elems: 64 v_sub + 32 v_min3(|.|,|.|) = 1.5 VALU/elem-visit.
// ---------------------------------------------------------------------------
__device__ __forceinline__ void scan_chunk(const float* __restrict__ db,
                                           int start, int end,
                                           const float qv[Q], float acc[Q]) {
    int j = start;
    for (; j + 8 <= end; j += 8) {
        const float v0 = db[j + 0], v1 = db[j + 1];
        const float v2 = db[j + 2], v3 = db[j + 3];
        const float v4 = db[j + 4], v5 = db[j + 5];
        const float v6 = db[j + 6], v7 = db[j + 7];
#pragma unroll
        for (int k = 0; k < Q; ++k) {
            const float q = qv[k];
            float a = acc[k];
            a = fminf(a, fminf(fabsf(q - v0), fabsf(q - v1)));
            a = fminf(a, fminf(fabsf(q - v2), fabsf(q - v3)));
            a = fminf(a, fminf(fabsf(q - v4), fabsf(q - v5)));
            a = fminf(a, fminf(fabsf(q - v6), fabsf(q - v7)));
            acc[k] = a;
        }
    }
    for (; j < end; ++j) {
        const float v = db[j];
#pragma unroll
        for (int k = 0; k < Q; ++k) acc[k] = fminf(acc[k], fabsf(qv[k] - v));
    }
}

__device__ __forceinline__ bool setup_thread(const float* __restrict__ x,
                                             const float* __restrict__ y,
                                             int n, int m, int* qbase_out,
                                             const float** db_out, int* dbn_out,
                                             float qv[Q]) {
    const int tid = blockIdx.y * blockDim.x + threadIdx.x;
    const int qbase = tid * Q;
    const int total = n + m;
    if (qbase >= total) return false;
    const float* qsrc;
    int qoff;
    if (qbase < n) { *db_out = y; *dbn_out = m; qsrc = x; qoff = qbase; }
    else           { *db_out = x; *dbn_out = n; qsrc = y; qoff = qbase - n; }
#pragma unroll
    for (int k = 0; k < Q; ++k) qv[k] = qsrc[qoff + k];
    *qbase_out = qbase;
    return true;
}

// Partial-store variant: partial[chunk][query], no init required, no atomics.
__global__ void chamfer_partial_kernel(const float* __restrict__ x,
                                       const float* __restrict__ y,
                                       int n, int m,
                                       float* __restrict__ partial) {
    int qbase, dbn;
    const float* db;
    float qv[Q];
    if (!setup_thread(x, y, n, m, &qbase, &db, &dbn, qv)) return;

    const int total = n + m;
    const int chunk_len = (dbn + CHUNKS - 1) / CHUNKS;
    const int start = blockIdx.x * chunk_len;
    const int end = min(start + chunk_len, dbn);

    float acc[Q];
#pragma unroll
    for (int k = 0; k < Q; ++k) acc[k] = FLT_MAX;
    scan_chunk(db, start, end, qv, acc);

    float* __restrict__ dst = partial + (size_t)blockIdx.x * total + qbase;
#pragma unroll
    for (int k = 0; k < Q; ++k) dst[k] = acc[k];
}

// Fallback when ws is small: atomicMin on uint bit patterns (needs 0xFF memset).
__global__ void chamfer_atomic_kernel(const float* __restrict__ x,
                                      const float* __restrict__ y,
                                      int n, int m,
                                      unsigned int* __restrict__ mins) {
    int qbase, dbn;
    const float* db;
    float qv[Q];
    if (!setup_thread(x, y, n, m, &qbase, &db, &dbn, qv)) return;

    const int chunk_len = (dbn + CHUNKS - 1) / CHUNKS;
    const int start = blockIdx.x * chunk_len;
    const int end = min(start + chunk_len, dbn);
    if (start >= end) return;

    float acc[Q];
#pragma unroll
    for (int k = 0; k < Q; ++k) acc[k] = FLT_MAX;
    scan_chunk(db, start, end, qv, acc);

#pragma unroll
    for (int k = 0; k < Q; ++k)
        atomicMin(&mins[qbase + k], __float_as_uint(acc[k]));
}

// Reduce 1: per query, min over `chunks` partials; block-sum x-part / y-part.
__global__ void chamfer_reduce1(const float* __restrict__ vals, int chunks,
                                int n, int m, double* __restrict__ bsums) {
    const int total = n + m;
    const int stride = gridDim.x * blockDim.x;
    double sx = 0.0, sy = 0.0;
    for (int q = blockIdx.x * blockDim.x + threadIdx.x; q < total; q += stride) {
        float mv = vals[q];
        for (int c = 1; c < chunks; ++c)
            mv = fminf(mv, vals[(size_t)c * total + q]);
        if (q < n) sx += (double)mv; else sy += (double)mv;
    }
    for (int off = 32; off > 0; off >>= 1) {
        sx += __shfl_down(sx, off);
        sy += __shfl_down(sy, off);
    }
    __shared__ double lsx[4], lsy[4];
    const int wave = threadIdx.x >> 6;
    if ((threadIdx.x & 63) == 0) { lsx[wave] = sx; lsy[wave] = sy; }
    __syncthreads();
    if (threadIdx.x == 0) {
        double tx = 0.0, ty = 0.0;
        for (int w = 0; w < (int)(blockDim.x >> 6); ++w) { tx += lsx[w]; ty += lsy[w]; }
        bsums[2 * blockIdx.x] = tx;
        bsums[2 * blockIdx.x + 1] = ty;
    }
}

// Reduce 2: fold NB2 block sums -> scalar loss.
__global__ void chamfer_reduce2(const double* __restrict__ bsums, int nb,
                                int n, int m, float* __restrict__ out) {
    double sx = 0.0, sy = 0.0;
    if ((int)threadIdx.x < nb) {
        sx = bsums[2 * threadIdx.x];
        sy = bsums[2 * threadIdx.x + 1];
    }
    for (int off = 32; off > 0; off >>= 1) {
        sx += __shfl_down(sx, off);
        sy += __shfl_down(sy, off);
    }
    if (threadIdx.x == 0) {
        const double a = (double)ALPHA;
        out[0] = (float)(a * sx / (double)n + (1.0 - a) * sy / (double)m);
    }
}

extern "C" void kernel_launch(void* const* d_in, const int* in_sizes, int n_in,
                              void* d_out, int out_size, void* d_ws, size_t ws_size,
                              hipStream_t stream) {
    const float* x = (const float*)d_in[0];
    const float* y = (const float*)d_in[1];
    const int n = in_sizes[0];
    const int m = in_sizes[1];
    float* out = (float*)d_out;
    const int total = n + m;

    const int qgroups = (total + Q - 1) / Q;
    const dim3 grid1(CHUNKS, (qgroups + TPB - 1) / TPB);

    const size_t partial_bytes = (size_t)CHUNKS * total * sizeof(float);
    const size_t partial_aligned = (partial_bytes + 255) & ~(size_t)255;
    const size_t bsum_bytes = 2 * NB2 * sizeof(double);

    if (ws_size >= partial_aligned + bsum_bytes) {
        // Fast path: non-atomic partial mins, no init needed.
        float* partial = (float*)d_ws;
        double* bsums = (double*)((char*)d_ws + partial_aligned);
        chamfer_partial_kernel<<<grid1, TPB, 0, stream>>>(x, y, n, m, partial);
        chamfer_reduce1<<<NB2, TPB, 0, stream>>>(partial, CHUNKS, n, m, bsums);
        chamfer_reduce2<<<1, 64, 0, stream>>>(bsums, NB2, n, m, out);
    } else {
        // Fallback: atomicMin into 0xFF-initialized uint mins.
        unsigned int* mins = (unsigned int*)d_ws;
        const size_t mins_bytes = (size_t)total * sizeof(unsigned int);
        const size_t mins_aligned = (mins_bytes + 255) & ~(size_t)255;
        double* bsums = (double*)((char*)d_ws + mins_aligned);
        hipMemsetAsync(mins, 0xFF, mins_bytes, stream);
        chamfer_atomic_kernel<<<grid1, TPB, 0, stream>>>(x, y, n, m, mins);
        chamfer_reduce1<<<NB2, TPB, 0, stream>>>((const float*)mins, 1, n, m, bsums);
        chamfer_reduce2<<<1, 64, 0, stream>>>(bsums, NB2, n, m, out);
    }
}

// Round 3
// 84.659 us; speedup vs baseline: 1.4922x; 1.4205x over previous
//
#include <hip/hip_runtime.h>
#include <cfloat>

#define TPB 256
#define Q 8          // queries per thread (register tile) in the scan kernel
#define CHUNKS 64    // db chunks (parallelism dimension)
#define RBLK 128     // queries per reduce1 block
#define ALPHA 0.5f

// ---------------------------------------------------------------------------
// Scan core: 8 queries per thread, db slice read via wave-uniform (scalar)
// loads. Per 8 db elems per query: 8 v_sub + 4 v_min3(abs,abs) = 1.5 VALU/visit.
// ---------------------------------------------------------------------------
__device__ __forceinline__ void scan_chunk(const float* __restrict__ db,
                                           int start, int end,
                                           const float qv[Q], float acc[Q]) {
    int j = start;
    for (; j + 8 <= end; j += 8) {
        const float v0 = db[j + 0], v1 = db[j + 1];
        const float v2 = db[j + 2], v3 = db[j + 3];
        const float v4 = db[j + 4], v5 = db[j + 5];
        const float v6 = db[j + 6], v7 = db[j + 7];
#pragma unroll
        for (int k = 0; k < Q; ++k) {
            const float q = qv[k];
            float a = acc[k];
            a = fminf(a, fminf(fabsf(q - v0), fabsf(q - v1)));
            a = fminf(a, fminf(fabsf(q - v2), fabsf(q - v3)));
            a = fminf(a, fminf(fabsf(q - v4), fabsf(q - v5)));
            a = fminf(a, fminf(fabsf(q - v6), fabsf(q - v7)));
            acc[k] = a;
        }
    }
    for (; j < end; ++j) {
        const float v = db[j];
#pragma unroll
        for (int k = 0; k < Q; ++k) acc[k] = fminf(acc[k], fabsf(qv[k] - v));
    }
}

// Partial-store: partial[chunk][query]. Always stores (FLT_MAX for empty
// chunks) so reduce1 never reads poisoned ws. No atomics, no init pass.
__global__ __launch_bounds__(TPB) void
chamfer_partial_kernel(const float* __restrict__ x, const float* __restrict__ y,
                       int n, int m, float* __restrict__ partial) {
    const int tid = blockIdx.y * blockDim.x + threadIdx.x;
    const int qbase = tid * Q;
    const int total = n + m;
    if (qbase >= total) return;

    const float* __restrict__ db;
    const float* qsrc;
    int dbn, qoff;
    if (qbase < n) { db = y; dbn = m; qsrc = x; qoff = qbase; }
    else           { db = x; dbn = n; qsrc = y; qoff = qbase - n; }

    float qv[Q];
#pragma unroll
    for (int k = 0; k < Q; ++k) qv[k] = qsrc[qoff + k];

    const int chunk_len = (dbn + CHUNKS - 1) / CHUNKS;
    const int start = blockIdx.x * chunk_len;
    const int end = min(start + chunk_len, dbn);

    float acc[Q];
#pragma unroll
    for (int k = 0; k < Q; ++k) acc[k] = FLT_MAX;
    if (start < end) scan_chunk(db, start, end, qv, acc);

    float* __restrict__ dst = partial + (size_t)blockIdx.x * total + qbase;
#pragma unroll
    for (int k = 0; k < Q; ++k) dst[k] = acc[k];
}

// Reduce 1: 256 blocks, each owns RBLK contiguous queries. 256 threads =
// RBLK queries x 2 chunk-halves; lanes read consecutive queries (coalesced).
__global__ __launch_bounds__(TPB) void
chamfer_reduce1(const float* __restrict__ vals, int n, int m,
                double* __restrict__ bsums) {
    const int total = n + m;
    const int lq = threadIdx.x & (RBLK - 1);   // query within block
    const int h = threadIdx.x >> 7;            // chunk half (0/1)
    const int q = blockIdx.x * RBLK + lq;

    float mv = FLT_MAX;
    if (q < total) {
        const int c0 = h * (CHUNKS / 2), c1 = c0 + CHUNKS / 2;
        for (int c = c0; c < c1; ++c)
            mv = fminf(mv, vals[(size_t)c * total + q]);
    }
    __shared__ float half1[RBLK];
    if (h == 1) half1[lq] = mv;
    __syncthreads();

    double sx = 0.0, sy = 0.0;
    if (h == 0 && q < total) {
        const float best = fminf(mv, half1[lq]);
        if (q < n) sx = (double)best; else sy = (double)best;
    }
    for (int off = 32; off > 0; off >>= 1) {
        sx += __shfl_down(sx, off);
        sy += __shfl_down(sy, off);
    }
    __shared__ double wsx[2], wsy[2];
    if (h == 0 && (threadIdx.x & 63) == 0) {
        wsx[threadIdx.x >> 6] = sx;
        wsy[threadIdx.x >> 6] = sy;
    }
    __syncthreads();
    if (threadIdx.x == 0) {
        bsums[2 * blockIdx.x]     = wsx[0] + wsx[1];
        bsums[2 * blockIdx.x + 1] = wsy[0] + wsy[1];
    }
}

// Reduce 2: fold nb block sums -> scalar loss.
__global__ __launch_bounds__(TPB) void
chamfer_reduce2(const double* __restrict__ bsums, int nb,
                int n, int m, float* __restrict__ out) {
    double sx = 0.0, sy = 0.0;
    for (int i = threadIdx.x; i < nb; i += blockDim.x) {
        sx += bsums[2 * i];
        sy += bsums[2 * i + 1];
    }
    for (int off = 32; off > 0; off >>= 1) {
        sx += __shfl_down(sx, off);
        sy += __shfl_down(sy, off);
    }
    __shared__ double lsx[4], lsy[4];
    const int wave = threadIdx.x >> 6;
    if ((threadIdx.x & 63) == 0) { lsx[wave] = sx; lsy[wave] = sy; }
    __syncthreads();
    if (threadIdx.x == 0) {
        double tx = 0.0, ty = 0.0;
        for (int w = 0; w < (int)(blockDim.x >> 6); ++w) { tx += lsx[w]; ty += lsy[w]; }
        const double a = (double)ALPHA;
        out[0] = (float)(a * tx / (double)n + (1.0 - a) * ty / (double)m);
    }
}

extern "C" void kernel_launch(void* const* d_in, const int* in_sizes, int n_in,
                              void* d_out, int out_size, void* d_ws, size_t ws_size,
                              hipStream_t stream) {
    const float* x = (const float*)d_in[0];
    const float* y = (const float*)d_in[1];
    const int n = in_sizes[0];
    const int m = in_sizes[1];
    float* out = (float*)d_out;
    const int total = n + m;

    const int qgroups = (total + Q - 1) / Q;
    const dim3 grid1(CHUNKS, (qgroups + TPB - 1) / TPB);
    const int nb1 = (total + RBLK - 1) / RBLK;

    const size_t partial_bytes = (size_t)CHUNKS * total * sizeof(float);
    const size_t partial_aligned = (partial_bytes + 255) & ~(size_t)255;

    float* partial = (float*)d_ws;
    double* bsums = (double*)((char*)d_ws + partial_aligned);

    chamfer_partial_kernel<<<grid1, TPB, 0, stream>>>(x, y, n, m, partial);
    chamfer_reduce1<<<nb1, TPB, 0, stream>>>(partial, n, m, bsums);
    chamfer_reduce2<<<1, TPB, 0, stream>>>(bsums, nb1, n, m, out);
}